// Round 1
// baseline (2750.972 us; speedup 1.0000x reference)
//
#include <hip/hip_runtime.h>
#include <cstdint>
#include <cstddef>
#include <cmath>

#define B_     8192
#define XD_    4096
#define ZD_    1024
#define XE_    64
#define H_     128
#define ZN_    (B_*ZD_)      /* 8388608 */
#define NHALF_ (ZN_/2)

// JAX threefry mode: 1 = partitionable (modern default), 0 = original split-half iota
#define RNG_PARTITIONABLE 1

// ---------------- threefry2x32 (bit-exact vs JAX) ----------------
__host__ __device__ __forceinline__ uint32_t rotl32_(uint32_t x, int r){ return (x<<r)|(x>>(32-r)); }

__host__ __device__ __forceinline__ void tf2x32(uint32_t k0, uint32_t k1,
                                                uint32_t x0, uint32_t x1,
                                                uint32_t* o0, uint32_t* o1){
  uint32_t k2 = k0 ^ k1 ^ 0x1BD11BDAu;
  x0 += k0; x1 += k1;
  x0 += x1; x1 = rotl32_(x1,13); x1 ^= x0;
  x0 += x1; x1 = rotl32_(x1,15); x1 ^= x0;
  x0 += x1; x1 = rotl32_(x1,26); x1 ^= x0;
  x0 += x1; x1 = rotl32_(x1, 6); x1 ^= x0;
  x0 += k1; x1 += k2 + 1u;
  x0 += x1; x1 = rotl32_(x1,17); x1 ^= x0;
  x0 += x1; x1 = rotl32_(x1,29); x1 ^= x0;
  x0 += x1; x1 = rotl32_(x1,16); x1 ^= x0;
  x0 += x1; x1 = rotl32_(x1,24); x1 ^= x0;
  x0 += k2; x1 += k0 + 2u;
  x0 += x1; x1 = rotl32_(x1,13); x1 ^= x0;
  x0 += x1; x1 = rotl32_(x1,15); x1 ^= x0;
  x0 += x1; x1 = rotl32_(x1,26); x1 ^= x0;
  x0 += x1; x1 = rotl32_(x1, 6); x1 ^= x0;
  x0 += k0; x1 += k1 + 3u;
  x0 += x1; x1 = rotl32_(x1,17); x1 ^= x0;
  x0 += x1; x1 = rotl32_(x1,29); x1 ^= x0;
  x0 += x1; x1 = rotl32_(x1,16); x1 ^= x0;
  x0 += x1; x1 = rotl32_(x1,24); x1 ^= x0;
  x0 += k1; x1 += k2 + 4u;
  x0 += x1; x1 = rotl32_(x1,13); x1 ^= x0;
  x0 += x1; x1 = rotl32_(x1,15); x1 ^= x0;
  x0 += x1; x1 = rotl32_(x1,26); x1 ^= x0;
  x0 += x1; x1 = rotl32_(x1, 6); x1 ^= x0;
  x0 += k2; x1 += k0 + 5u;
  *o0 = x0; *o1 = x1;
}

// XLA ErfInv32 (Giles polynomial) — matches jnp erf_inv within ~1 ulp
__device__ __forceinline__ float erfinv_(float x){
  float w = -log1pf(-x*x);
  float p;
  if (w < 5.0f){
    w -= 2.5f;
    p = 2.81022636e-08f;
    p = fmaf(p, w, 3.43273939e-07f);
    p = fmaf(p, w, -3.5233877e-06f);
    p = fmaf(p, w, -4.39150654e-06f);
    p = fmaf(p, w, 0.00021858087f);
    p = fmaf(p, w, -0.00125372503f);
    p = fmaf(p, w, -0.00417768164f);
    p = fmaf(p, w, 0.246640727f);
    p = fmaf(p, w, 1.50140941f);
  } else {
    w = sqrtf(w) - 3.0f;
    p = -0.000200214257f;
    p = fmaf(p, w, 0.000100950558f);
    p = fmaf(p, w, 0.00134934322f);
    p = fmaf(p, w, -0.00367342844f);
    p = fmaf(p, w, 0.00573950773f);
    p = fmaf(p, w, -0.0076224613f);
    p = fmaf(p, w, 0.00943887047f);
    p = fmaf(p, w, 1.00167406f);
    p = fmaf(p, w, 2.83297682f);
  }
  return p * x;
}

__device__ __forceinline__ float bits_to_normal(uint32_t bits){
  // jax.random.normal f32: uniform in [nextafter(-1,0), 1), then sqrt(2)*erfinv
  float f = __uint_as_float((bits >> 9) | 0x3f800000u) - 1.0f;  // [0,1)
  float u = fmaxf(-0.99999994f, fmaf(f, 2.0f, -0.99999994f));   // maxval-minval rounds to 2.0f
  return 1.41421356f * erfinv_(u);
}

__device__ __forceinline__ float rng_normal(uint32_t k0, uint32_t k1, uint32_t idx){
#if RNG_PARTITIONABLE
  uint32_t o0, o1; tf2x32(k0, k1, 0u, idx, &o0, &o1);
  return bits_to_normal(o0 ^ o1);
#else
  uint32_t i = (idx < NHALF_) ? idx : idx - NHALF_;
  uint32_t o0, o1; tf2x32(k0, k1, i, i + NHALF_, &o0, &o1);
  return bits_to_normal((idx < NHALF_) ? o0 : o1);
#endif
}

// ---------------- tiny weight-prep kernels ----------------
// S = I + saWo @ saWv ; U = caWo @ caWv   (Wv = rows [256:384] of Wqkv)
__global__ void k_prepA(const float* __restrict__ saWo, const float* __restrict__ saWqkv,
                        const float* __restrict__ caWo, const float* __restrict__ caWqkv,
                        float* __restrict__ S, float* __restrict__ U){
  int blk = blockIdx.x, tid = threadIdx.x;
  int idx = (blk & 255) * 64 + tid;
  int i = idx >> 7, j = idx & 127;
  if (blk < 256){
    float acc = (i == j) ? 1.0f : 0.0f;
    for (int k = 0; k < H_; ++k) acc += saWo[i*H_ + k] * saWqkv[(2*H_ + k)*H_ + j];
    S[idx] = acc;
  } else {
    float acc = 0.0f;
    for (int k = 0; k < H_; ++k) acc += caWo[i*H_ + k] * caWqkv[(2*H_ + k)*H_ + j];
    U[idx] = acc;
  }
}

// s0 = saWo@sabv + sabo ; u0 = caWo@cabv + cabo ; cb = W2^T b2
__global__ void k_prepB(const float* __restrict__ saWo, const float* __restrict__ sabqkv, const float* __restrict__ sabo,
                        const float* __restrict__ caWo, const float* __restrict__ cabqkv, const float* __restrict__ cabo,
                        const float* __restrict__ W2, const float* __restrict__ pb2,
                        float* __restrict__ s0, float* __restrict__ u0, float* __restrict__ cb){
  int blk = blockIdx.x, tid = threadIdx.x;
  if (blk < 2){
    int i = blk*64 + tid;
    float acc = sabo[i];
    for (int k = 0; k < H_; ++k) acc += saWo[i*H_ + k] * sabqkv[2*H_ + k];
    s0[i] = acc;
  } else if (blk < 4){
    int i = (blk-2)*64 + tid;
    float acc = cabo[i];
    for (int k = 0; k < H_; ++k) acc += caWo[i*H_ + k] * cabqkv[2*H_ + k];
    u0[i] = acc;
  } else {
    int j = (blk-4)*64 + tid;
    float acc = 0.0f;
    for (int c = 0; c < XD_; ++c) acc += pb2[c] * W2[(size_t)c*H_ + j];
    cb[j] = acc;
  }
}

// M = W2^T W2 (128x128)
__global__ void k_prepM(const float* __restrict__ W2, float* __restrict__ M){
  int idx = blockIdx.x*64 + threadIdx.x;  // 16384
  int j1 = idx >> 7, j2 = idx & 127;
  float acc = 0.0f;
  for (int c = 0; c < XD_; ++c) acc += W2[(size_t)c*H_ + j1] * W2[(size_t)c*H_ + j2];
  M[idx] = acc;
}

// T = S@xpW (128x64); R = U@zpW (128x1024); t0 = S@xpb + s0; r0 = U@zpb + u0
__global__ void k_prepTR(const float* __restrict__ S, const float* __restrict__ U,
                         const float* __restrict__ xpW, const float* __restrict__ zpW,
                         const float* __restrict__ xpb, const float* __restrict__ zpb,
                         const float* __restrict__ s0, const float* __restrict__ u0,
                         float* __restrict__ T, float* __restrict__ R,
                         float* __restrict__ t0, float* __restrict__ r0v){
  int blk = blockIdx.x, tid = threadIdx.x;
  if (blk < 128){
    int idx = blk*64 + tid;              // 8192
    int i = idx >> 6, e = idx & 63;
    float acc = 0.0f;
    for (int m = 0; m < H_; ++m) acc += S[i*H_ + m] * xpW[m*XE_ + e];
    T[idx] = acc;
  } else if (blk < 2176){
    int idx = (blk-128)*64 + tid;        // 131072
    int i = idx >> 10, k = idx & 1023;
    float acc = 0.0f;
    for (int m = 0; m < H_; ++m) acc += U[i*H_ + m] * zpW[(size_t)m*ZD_ + k];
    R[idx] = acc;
  } else if (blk < 2178){
    int i = (blk-2176)*64 + tid;
    float acc = s0[i];
    for (int m = 0; m < H_; ++m) acc += S[i*H_ + m] * xpb[m];
    t0[i] = acc;
  } else {
    int i = (blk-2178)*64 + tid;
    float acc = u0[i];
    for (int m = 0; m < H_; ++m) acc += U[i*H_ + m] * zpb[m];
    r0v[i] = acc;
  }
}

// WX[c][j]: j<128 -> W2[c][j]; j>=128 -> Q^T[c][j-128] = sum_e T[j-128][e]*embW[e][c].  q0 = T@embb + t0.
__global__ void k_prepWX(const float* __restrict__ W2, const float* __restrict__ T,
                         const float* __restrict__ embW, const float* __restrict__ embb,
                         const float* __restrict__ t0,
                         float* __restrict__ WX, float* __restrict__ q0){
  int idx = blockIdx.x*256 + threadIdx.x;   // 4096*256
  int c = idx >> 8, j = idx & 255;
  float v;
  if (j < H_) v = W2[(size_t)c*H_ + j];
  else {
    int i = j - H_;
    float acc = 0.0f;
    for (int e = 0; e < XE_; ++e) acc += T[i*XE_ + e] * embW[(size_t)e*XD_ + c];
    v = acc;
  }
  WX[idx] = v;
  if (idx < H_){
    float acc = t0[idx];
    for (int e = 0; e < XE_; ++e) acc += T[idx*XE_ + e] * embb[e];
    q0[idx] = acc;
  }
}

// W2T[h][c] = W2[c][h]
__global__ void k_prepW2T(const float* __restrict__ W2, float* __restrict__ W2T){
  int idx = blockIdx.x*256 + threadIdx.x;   // 524288
  int c = idx >> 7, h = idx & 127;
  W2T[(size_t)h*XD_ + c] = W2[idx];
}

// ---------------- z0 generation ----------------
__global__ void k_genz0(float* __restrict__ z, uint32_t k0, uint32_t k1){
  uint32_t i = blockIdx.x*256u + threadIdx.x;
  z[i] = rng_normal(k0, k1, i);
}

// ---------------- x-pass: cneg = 2*(cb - x@W2), h1pre = Q@x + q0 ----------------
__global__ __launch_bounds__(256) void k_xpass(const float* __restrict__ x, const float* __restrict__ WX,
                        const float* __restrict__ cb, const float* __restrict__ q0,
                        float* __restrict__ cneg, float* __restrict__ h1pre){
  __shared__ float xs[16][36];
  __shared__ float ws[32][260];
  const int tid = threadIdx.x;
  const int b0 = blockIdx.x * 16;
  const int c0 = (tid & 63) * 4;
  const int r0 = (tid >> 6) * 4;
  float acc[4][4] = {};
  for (int k0 = 0; k0 < XD_; k0 += 32){
    if (tid < 128){
      int r = tid >> 3, c4 = (tid & 7) * 4;
      *(float4*)&xs[r][c4] = *(const float4*)&x[(size_t)(b0 + r)*XD_ + k0 + c4];
    }
    {
      int c4 = (tid & 63) * 4;
      int kk0 = tid >> 6;
      #pragma unroll
      for (int it = 0; it < 8; ++it){
        int kk = kk0 + it*4;
        *(float4*)&ws[kk][c4] = *(const float4*)&WX[(size_t)(k0 + kk)*256 + c4];
      }
    }
    __syncthreads();
    #pragma unroll 8
    for (int kk = 0; kk < 32; ++kk){
      float4 wv = *(const float4*)&ws[kk][c0];
      #pragma unroll
      for (int r = 0; r < 4; ++r){
        float xv = xs[r0 + r][kk];
        acc[r][0] = fmaf(xv, wv.x, acc[r][0]);
        acc[r][1] = fmaf(xv, wv.y, acc[r][1]);
        acc[r][2] = fmaf(xv, wv.z, acc[r][2]);
        acc[r][3] = fmaf(xv, wv.w, acc[r][3]);
      }
    }
    __syncthreads();
  }
  #pragma unroll
  for (int r = 0; r < 4; ++r){
    int b = b0 + r0 + r;
    #pragma unroll
    for (int c = 0; c < 4; ++c){
      int j = c0 + c;
      float v = acc[r][c];
      if (j < H_) cneg[(size_t)b*H_ + j] = 2.0f*(cb[j] - v);
      else        h1pre[(size_t)b*H_ + (j - H_)] = v + q0[j - H_];
    }
  }
}

// ---------------- one Langevin step ----------------
__global__ __launch_bounds__(256) void k_step(float* __restrict__ z,
    const float* __restrict__ W1, const float* __restrict__ b1,
    const float* __restrict__ M, const float* __restrict__ cneg,
    uint32_t key0, uint32_t key1, float hstep, float nscale){
  __shared__ float wbuf[16896];      // phase1: [64][132] W1^T tile ; phase3: [128][132] W1 tile
  __shared__ float zs[32][68];
  __shared__ float ha[32][132];
  __shared__ float gl[32][132];
  const int tid = threadIdx.x;
  const int b0 = blockIdx.x * 32;

  // phase 1: h = z @ W1^T + b1   (32 x 128, K=1024)
  const int c0 = (tid & 31) * 4;
  const int r0 = (tid >> 5) * 4;
  float acc[4][4] = {};
  for (int kt = 0; kt < ZD_; kt += 64){
    {
      int zr = tid >> 4, zc = (tid & 15) * 4;
      *(float4*)&zs[zr][zc]    = *(const float4*)&z[(size_t)(b0+zr)*ZD_ + kt + zc];
      *(float4*)&zs[zr+16][zc] = *(const float4*)&z[(size_t)(b0+zr+16)*ZD_ + kt + zc];
    }
    {
      int hh0 = tid >> 4, k4 = (tid & 15) * 4;
      #pragma unroll
      for (int it = 0; it < 8; ++it){
        int hh = hh0 + 16*it;
        float4 v = *(const float4*)&W1[(size_t)hh*ZD_ + kt + k4];
        wbuf[(k4+0)*132 + hh] = v.x;
        wbuf[(k4+1)*132 + hh] = v.y;
        wbuf[(k4+2)*132 + hh] = v.z;
        wbuf[(k4+3)*132 + hh] = v.w;
      }
    }
    __syncthreads();
    #pragma unroll 4
    for (int kk = 0; kk < 64; ++kk){
      float4 wv = *(const float4*)&wbuf[kk*132 + c0];
      #pragma unroll
      for (int r = 0; r < 4; ++r){
        float zv = zs[r0 + r][kk];
        acc[r][0] = fmaf(zv, wv.x, acc[r][0]);
        acc[r][1] = fmaf(zv, wv.y, acc[r][1]);
        acc[r][2] = fmaf(zv, wv.z, acc[r][2]);
        acc[r][3] = fmaf(zv, wv.w, acc[r][3]);
      }
    }
    __syncthreads();
  }
  {
    float4 bv = *(const float4*)&b1[c0];
    #pragma unroll
    for (int r = 0; r < 4; ++r){
      ha[r0+r][c0+0] = acc[r][0] + bv.x;
      ha[r0+r][c0+1] = acc[r][1] + bv.y;
      ha[r0+r][c0+2] = acc[r][2] + bv.z;
      ha[r0+r][c0+3] = acc[r][3] + bv.w;
    }
  }
  __syncthreads();

  // phase 2: g = (h>0) ? 2*(relu(h)@M) + cneg : 0
  float g2[4][4] = {};
  for (int j = 0; j < H_; ++j){
    float4 mv = *(const float4*)&M[j*H_ + c0];
    #pragma unroll
    for (int r = 0; r < 4; ++r){
      float av = fmaxf(ha[r0+r][j], 0.0f);
      g2[r][0] = fmaf(av, mv.x, g2[r][0]);
      g2[r][1] = fmaf(av, mv.y, g2[r][1]);
      g2[r][2] = fmaf(av, mv.z, g2[r][2]);
      g2[r][3] = fmaf(av, mv.w, g2[r][3]);
    }
  }
  #pragma unroll
  for (int r = 0; r < 4; ++r){
    float4 cn = *(const float4*)&cneg[(size_t)(b0+r0+r)*H_ + c0];
    gl[r0+r][c0+0] = (ha[r0+r][c0+0] > 0.f) ? fmaf(2.f, g2[r][0], cn.x) : 0.f;
    gl[r0+r][c0+1] = (ha[r0+r][c0+1] > 0.f) ? fmaf(2.f, g2[r][1], cn.y) : 0.f;
    gl[r0+r][c0+2] = (ha[r0+r][c0+2] > 0.f) ? fmaf(2.f, g2[r][2], cn.z) : 0.f;
    gl[r0+r][c0+3] = (ha[r0+r][c0+3] > 0.f) ? fmaf(2.f, g2[r][3], cn.w) : 0.f;
  }
  __syncthreads();

  // phase 3: z = (z - hstep*(g @ W1)) + nscale*noise
  const int r3 = tid >> 4;          // rows r3, r3+16
  const int c3 = (tid & 15) * 8;
  for (int kt = 0; kt < ZD_; kt += 128){
    {
      int hh0 = tid >> 5, k4 = (tid & 31) * 4;
      #pragma unroll
      for (int it = 0; it < 16; ++it){
        int hh = hh0 + 8*it;
        *(float4*)&wbuf[hh*132 + k4] = *(const float4*)&W1[(size_t)hh*ZD_ + kt + k4];
      }
    }
    __syncthreads();
    float a0[8] = {0,0,0,0,0,0,0,0};
    float a1[8] = {0,0,0,0,0,0,0,0};
    #pragma unroll 4
    for (int h = 0; h < H_; ++h){
      const float* wr = &wbuf[h*132 + c3];
      float4 w0  = *(const float4*)wr;
      float4 w1v = *(const float4*)(wr + 4);
      float ga = gl[r3][h];
      float gb = gl[r3+16][h];
      a0[0]=fmaf(ga,w0.x,a0[0]); a0[1]=fmaf(ga,w0.y,a0[1]); a0[2]=fmaf(ga,w0.z,a0[2]); a0[3]=fmaf(ga,w0.w,a0[3]);
      a0[4]=fmaf(ga,w1v.x,a0[4]); a0[5]=fmaf(ga,w1v.y,a0[5]); a0[6]=fmaf(ga,w1v.z,a0[6]); a0[7]=fmaf(ga,w1v.w,a0[7]);
      a1[0]=fmaf(gb,w0.x,a1[0]); a1[1]=fmaf(gb,w0.y,a1[1]); a1[2]=fmaf(gb,w0.z,a1[2]); a1[3]=fmaf(gb,w0.w,a1[3]);
      a1[4]=fmaf(gb,w1v.x,a1[4]); a1[5]=fmaf(gb,w1v.y,a1[5]); a1[6]=fmaf(gb,w1v.z,a1[6]); a1[7]=fmaf(gb,w1v.w,a1[7]);
    }
    size_t base0 = (size_t)(b0 + r3)*ZD_ + kt + c3;
    size_t base1 = (size_t)(b0 + r3 + 16)*ZD_ + kt + c3;
    float4 z00 = *(const float4*)&z[base0];
    float4 z01 = *(const float4*)&z[base0 + 4];
    float4 z10 = *(const float4*)&z[base1];
    float4 z11 = *(const float4*)&z[base1 + 4];
    float t;
    t = fmaf(-hstep, a0[0], z00.x); z00.x = fmaf(nscale, rng_normal(key0,key1,(uint32_t)(base0+0)), t);
    t = fmaf(-hstep, a0[1], z00.y); z00.y = fmaf(nscale, rng_normal(key0,key1,(uint32_t)(base0+1)), t);
    t = fmaf(-hstep, a0[2], z00.z); z00.z = fmaf(nscale, rng_normal(key0,key1,(uint32_t)(base0+2)), t);
    t = fmaf(-hstep, a0[3], z00.w); z00.w = fmaf(nscale, rng_normal(key0,key1,(uint32_t)(base0+3)), t);
    t = fmaf(-hstep, a0[4], z01.x); z01.x = fmaf(nscale, rng_normal(key0,key1,(uint32_t)(base0+4)), t);
    t = fmaf(-hstep, a0[5], z01.y); z01.y = fmaf(nscale, rng_normal(key0,key1,(uint32_t)(base0+5)), t);
    t = fmaf(-hstep, a0[6], z01.z); z01.z = fmaf(nscale, rng_normal(key0,key1,(uint32_t)(base0+6)), t);
    t = fmaf(-hstep, a0[7], z01.w); z01.w = fmaf(nscale, rng_normal(key0,key1,(uint32_t)(base0+7)), t);
    t = fmaf(-hstep, a1[0], z10.x); z10.x = fmaf(nscale, rng_normal(key0,key1,(uint32_t)(base1+0)), t);
    t = fmaf(-hstep, a1[1], z10.y); z10.y = fmaf(nscale, rng_normal(key0,key1,(uint32_t)(base1+1)), t);
    t = fmaf(-hstep, a1[2], z10.z); z10.z = fmaf(nscale, rng_normal(key0,key1,(uint32_t)(base1+2)), t);
    t = fmaf(-hstep, a1[3], z10.w); z10.w = fmaf(nscale, rng_normal(key0,key1,(uint32_t)(base1+3)), t);
    t = fmaf(-hstep, a1[4], z11.x); z11.x = fmaf(nscale, rng_normal(key0,key1,(uint32_t)(base1+4)), t);
    t = fmaf(-hstep, a1[5], z11.y); z11.y = fmaf(nscale, rng_normal(key0,key1,(uint32_t)(base1+5)), t);
    t = fmaf(-hstep, a1[6], z11.z); z11.z = fmaf(nscale, rng_normal(key0,key1,(uint32_t)(base1+6)), t);
    t = fmaf(-hstep, a1[7], z11.w); z11.w = fmaf(nscale, rng_normal(key0,key1,(uint32_t)(base1+7)), t);
    *(float4*)&z[base0]     = z00;
    *(float4*)&z[base0 + 4] = z01;
    *(float4*)&z[base1]     = z10;
    *(float4*)&z[base1 + 4] = z11;
    __syncthreads();
  }
}

// ---------------- final z pass: hfin = relu(W1 z + b1), capre = R z + r0 ----------------
__global__ __launch_bounds__(256) void k_finalz(const float* __restrict__ z, const float* __restrict__ W1,
     const float* __restrict__ Rm, const float* __restrict__ b1, const float* __restrict__ r0v,
     float* __restrict__ hfin, float* __restrict__ capre){
  __shared__ float wt[64*260];
  __shared__ float zs[32][68];
  const int tid = threadIdx.x;
  const int b0 = blockIdx.x * 32;
  const int c0 = (tid & 63) * 4;
  const int r0 = (tid >> 6) * 8;
  float acc[8][4] = {};
  for (int kt = 0; kt < ZD_; kt += 64){
    {
      int zr = tid >> 4, zc = (tid & 15) * 4;
      *(float4*)&zs[zr][zc]    = *(const float4*)&z[(size_t)(b0+zr)*ZD_ + kt + zc];
      *(float4*)&zs[zr+16][zc] = *(const float4*)&z[(size_t)(b0+zr+16)*ZD_ + kt + zc];
    }
    {
      int jj = tid >> 4, k4 = (tid & 15) * 4;
      #pragma unroll
      for (int it = 0; it < 16; ++it){
        int j = jj + 16*it;
        const float* src = (j < H_) ? &W1[(size_t)j*ZD_ + kt + k4] : &Rm[(size_t)(j-H_)*ZD_ + kt + k4];
        float4 v = *(const float4*)src;
        wt[(k4+0)*260 + j] = v.x;
        wt[(k4+1)*260 + j] = v.y;
        wt[(k4+2)*260 + j] = v.z;
        wt[(k4+3)*260 + j] = v.w;
      }
    }
    __syncthreads();
    #pragma unroll 2
    for (int kk = 0; kk < 64; ++kk){
      float4 wv = *(const float4*)&wt[kk*260 + c0];
      #pragma unroll
      for (int r = 0; r < 8; ++r){
        float zv = zs[r0 + r][kk];
        acc[r][0] = fmaf(zv, wv.x, acc[r][0]);
        acc[r][1] = fmaf(zv, wv.y, acc[r][1]);
        acc[r][2] = fmaf(zv, wv.z, acc[r][2]);
        acc[r][3] = fmaf(zv, wv.w, acc[r][3]);
      }
    }
    __syncthreads();
  }
  #pragma unroll
  for (int r = 0; r < 8; ++r){
    int b = b0 + r0 + r;
    #pragma unroll
    for (int c = 0; c < 4; ++c){
      int j = c0 + c;
      float v = acc[r][c];
      if (j < H_) hfin[(size_t)b*H_ + j] = fmaxf(v + b1[j], 0.0f);
      else        capre[(size_t)b*H_ + (j - H_)] = v + r0v[j - H_];
    }
  }
}

// ---------------- x_recon = hfin @ W2^T + b2 ----------------
__global__ __launch_bounds__(256) void k_xrecon(const float* __restrict__ hfin,
    const float* __restrict__ W2T, const float* __restrict__ b2, float* __restrict__ out){
  __shared__ float as[32][132];
  __shared__ float wt[16896];
  const int tid = threadIdx.x;
  const int b0 = blockIdx.x * 32;
  {
    int r = tid >> 3, c4 = (tid & 7) * 4;
    #pragma unroll
    for (int it = 0; it < 4; ++it)
      *(float4*)&as[r][c4 + 32*it] = *(const float4*)&hfin[(size_t)(b0+r)*H_ + c4 + 32*it];
  }
  const int r0 = (tid >> 4) * 2;
  const int c0 = (tid & 15) * 8;
  for (int ct = 0; ct < XD_; ct += 128){
    {
      int h0 = tid >> 5, c4 = (tid & 31) * 4;
      #pragma unroll
      for (int it = 0; it < 16; ++it){
        int hh = h0 + 8*it;
        *(float4*)&wt[hh*132 + c4] = *(const float4*)&W2T[(size_t)hh*XD_ + ct + c4];
      }
    }
    __syncthreads();
    float a0[8] = {0,0,0,0,0,0,0,0};
    float a1[8] = {0,0,0,0,0,0,0,0};
    #pragma unroll 4
    for (int h = 0; h < H_; ++h){
      const float* wr = &wt[h*132 + c0];
      float4 w0  = *(const float4*)wr;
      float4 w1v = *(const float4*)(wr + 4);
      float ga = as[r0][h], gb = as[r0+1][h];
      a0[0]=fmaf(ga,w0.x,a0[0]); a0[1]=fmaf(ga,w0.y,a0[1]); a0[2]=fmaf(ga,w0.z,a0[2]); a0[3]=fmaf(ga,w0.w,a0[3]);
      a0[4]=fmaf(ga,w1v.x,a0[4]); a0[5]=fmaf(ga,w1v.y,a0[5]); a0[6]=fmaf(ga,w1v.z,a0[6]); a0[7]=fmaf(ga,w1v.w,a0[7]);
      a1[0]=fmaf(gb,w0.x,a1[0]); a1[1]=fmaf(gb,w0.y,a1[1]); a1[2]=fmaf(gb,w0.z,a1[2]); a1[3]=fmaf(gb,w0.w,a1[3]);
      a1[4]=fmaf(gb,w1v.x,a1[4]); a1[5]=fmaf(gb,w1v.y,a1[5]); a1[6]=fmaf(gb,w1v.z,a1[6]); a1[7]=fmaf(gb,w1v.w,a1[7]);
    }
    float4 bz0 = *(const float4*)&b2[ct + c0];
    float4 bz1 = *(const float4*)&b2[ct + c0 + 4];
    *(float4*)&out[(size_t)(b0+r0)*XD_ + ct + c0]       = make_float4(a0[0]+bz0.x, a0[1]+bz0.y, a0[2]+bz0.z, a0[3]+bz0.w);
    *(float4*)&out[(size_t)(b0+r0)*XD_ + ct + c0 + 4]   = make_float4(a0[4]+bz1.x, a0[5]+bz1.y, a0[6]+bz1.z, a0[7]+bz1.w);
    *(float4*)&out[(size_t)(b0+r0+1)*XD_ + ct + c0]     = make_float4(a1[0]+bz0.x, a1[1]+bz0.y, a1[2]+bz0.z, a1[3]+bz0.w);
    *(float4*)&out[(size_t)(b0+r0+1)*XD_ + ct + c0 + 4] = make_float4(a1[4]+bz1.x, a1[5]+bz1.y, a1[6]+bz1.z, a1[7]+bz1.w);
    __syncthreads();
  }
}

// ---------------- per-row transformer tail -> y_pred ----------------
__device__ __forceinline__ float wsum64(float v){
  #pragma unroll
  for (int off = 32; off > 0; off >>= 1) v += __shfl_xor(v, off, 64);
  return v;
}

__global__ __launch_bounds__(256) void k_tail(
    const float* __restrict__ h1pre, const float* __restrict__ capre,
    const float* __restrict__ ln1g, const float* __restrict__ ln1b,
    const float* __restrict__ ln2g, const float* __restrict__ ln2b,
    const float* __restrict__ ln3g, const float* __restrict__ ln3b,
    const float* __restrict__ fW1, const float* __restrict__ fb1,
    const float* __restrict__ fW2, const float* __restrict__ fb2,
    const float* __restrict__ outW, const float* __restrict__ outb,
    float* __restrict__ y){
  __shared__ float sh2[4][128];
  __shared__ float st1[4][128];
  const int tid = threadIdx.x;
  const int w = tid >> 6;
  const int l = tid & 63;
  const int b = blockIdx.x * 4 + w;
  const float* hp = h1pre + (size_t)b * H_;
  const float* cp = capre + (size_t)b * H_;
  float x0 = hp[l], x1 = hp[l+64];
  float m = wsum64(x0 + x1) * (1.0f/128.0f);
  float d0 = x0 - m, d1 = x1 - m;
  float v = wsum64(d0*d0 + d1*d1) * (1.0f/128.0f);
  float rs = rsqrtf(v + 1e-5f);
  float h1a = d0 * rs * ln1g[l]    + ln1b[l];
  float h1b = d1 * rs * ln1g[l+64] + ln1b[l+64];
  x0 = h1a + cp[l]; x1 = h1b + cp[l+64];
  m = wsum64(x0 + x1) * (1.0f/128.0f);
  d0 = x0 - m; d1 = x1 - m;
  v = wsum64(d0*d0 + d1*d1) * (1.0f/128.0f);
  rs = rsqrtf(v + 1e-5f);
  float h2a = d0 * rs * ln2g[l]    + ln2b[l];
  float h2b = d1 * rs * ln2g[l+64] + ln2b[l+64];
  sh2[w][l] = h2a; sh2[w][l+64] = h2b;
  __syncthreads();
  float ta = fb1[l], tb = fb1[l+64];
  #pragma unroll 8
  for (int m4 = 0; m4 < H_; m4 += 4){
    float4 hv = *(const float4*)&sh2[w][m4];
    float4 wa = *(const float4*)&fW1[(size_t)l*H_ + m4];
    float4 wb = *(const float4*)&fW1[(size_t)(l+64)*H_ + m4];
    ta = fmaf(wa.x, hv.x, ta); ta = fmaf(wa.y, hv.y, ta); ta = fmaf(wa.z, hv.z, ta); ta = fmaf(wa.w, hv.w, ta);
    tb = fmaf(wb.x, hv.x, tb); tb = fmaf(wb.y, hv.y, tb); tb = fmaf(wb.z, hv.z, tb); tb = fmaf(wb.w, hv.w, tb);
  }
  ta = fmaxf(ta, 0.0f); tb = fmaxf(tb, 0.0f);
  st1[w][l] = ta; st1[w][l+64] = tb;
  __syncthreads();
  float fa = fb2[l], fbv = fb2[l+64];
  #pragma unroll 8
  for (int m4 = 0; m4 < H_; m4 += 4){
    float4 tv = *(const float4*)&st1[w][m4];
    float4 wa = *(const float4*)&fW2[(size_t)l*H_ + m4];
    float4 wb = *(const float4*)&fW2[(size_t)(l+64)*H_ + m4];
    fa  = fmaf(wa.x, tv.x, fa);  fa  = fmaf(wa.y, tv.y, fa);  fa  = fmaf(wa.z, tv.z, fa);  fa  = fmaf(wa.w, tv.w, fa);
    fbv = fmaf(wb.x, tv.x, fbv); fbv = fmaf(wb.y, tv.y, fbv); fbv = fmaf(wb.z, tv.z, fbv); fbv = fmaf(wb.w, tv.w, fbv);
  }
  x0 = h2a + fa; x1 = h2b + fbv;
  m = wsum64(x0 + x1) * (1.0f/128.0f);
  d0 = x0 - m; d1 = x1 - m;
  v = wsum64(d0*d0 + d1*d1) * (1.0f/128.0f);
  rs = rsqrtf(v + 1e-5f);
  float h3a = d0 * rs * ln3g[l]    + ln3b[l];
  float h3b = d1 * rs * ln3g[l+64] + ln3b[l+64];
  float py = wsum64(outW[l]*h3a + outW[l+64]*h3b);
  if (l == 0) y[b] = py + outb[0];
}

// ---------------- host ----------------
static void make_keys(uint32_t ks[11][2]){
#if RNG_PARTITIONABLE
  for (uint32_t i = 0; i < 11; ++i) tf2x32(0u, 42u, 0u, i, &ks[i][0], &ks[i][1]);
#else
  uint32_t out[22];
  for (uint32_t i = 0; i < 11; ++i){
    uint32_t a, b; tf2x32(0u, 42u, i, 11u + i, &a, &b);
    out[i] = a; out[11u + i] = b;
  }
  for (int i = 0; i < 11; ++i){ ks[i][0] = out[2*i]; ks[i][1] = out[2*i+1]; }
#endif
}

extern "C" void kernel_launch(void* const* d_in, const int* in_sizes, int n_in,
                              void* d_out, int out_size, void* d_ws, size_t ws_size,
                              hipStream_t stream){
  const float* x      = (const float*)d_in[0];
  const float* pxW1   = (const float*)d_in[1];
  const float* pxb1   = (const float*)d_in[2];
  const float* pxW2   = (const float*)d_in[3];
  const float* pxb2   = (const float*)d_in[4];
  const float* embW   = (const float*)d_in[5];
  const float* embb   = (const float*)d_in[6];
  const float* xpW    = (const float*)d_in[7];
  const float* xpb    = (const float*)d_in[8];
  const float* zpW    = (const float*)d_in[9];
  const float* zpb    = (const float*)d_in[10];
  const float* saWqkv = (const float*)d_in[11];
  const float* sabqkv = (const float*)d_in[12];
  const float* saWo   = (const float*)d_in[13];
  const float* sabo   = (const float*)d_in[14];
  const float* caWqkv = (const float*)d_in[15];
  const float* cabqkv = (const float*)d_in[16];
  const float* caWo   = (const float*)d_in[17];
  const float* cabo   = (const float*)d_in[18];
  const float* fW1    = (const float*)d_in[19];
  const float* fb1    = (const float*)d_in[20];
  const float* fW2    = (const float*)d_in[21];
  const float* fb2    = (const float*)d_in[22];
  const float* ln1g   = (const float*)d_in[23];
  const float* ln1b   = (const float*)d_in[24];
  const float* ln2g   = (const float*)d_in[25];
  const float* ln2b   = (const float*)d_in[26];
  const float* ln3g   = (const float*)d_in[27];
  const float* ln3b   = (const float*)d_in[28];
  const float* outW   = (const float*)d_in[29];
  const float* outb   = (const float*)d_in[30];
  (void)in_sizes; (void)n_in; (void)out_size; (void)ws_size;

  float* ws   = (float*)d_ws;
  float* z     = ws;                          // 8388608
  float* cneg  = z + (size_t)ZN_;             // 1048576
  float* h1pre = cneg + (size_t)B_*H_;        // 1048576
  float* capre = h1pre + (size_t)B_*H_;       // 1048576
  float* hfin  = capre + (size_t)B_*H_;       // 1048576
  float* WX    = hfin + (size_t)B_*H_;        // 1048576
  float* Rm    = WX + (size_t)XD_*256;        // 131072
  float* W2T   = Rm + (size_t)H_*ZD_;         // 524288
  float* Mm    = W2T + (size_t)H_*XD_;        // 16384
  float* Sm    = Mm + H_*H_;                  // 16384
  float* Um    = Sm + H_*H_;                  // 16384
  float* Tm    = Um + H_*H_;                  // 8192
  float* vs0   = Tm + H_*XE_;
  float* vu0   = vs0 + H_;
  float* vt0   = vu0 + H_;
  float* vq0   = vt0 + H_;
  float* vr0   = vq0 + H_;
  float* vcb   = vr0 + H_;

  uint32_t ks[11][2];
  make_keys(ks);
  const float hstep  = 0.005f;            // 0.5 * STEP
  const float nscale = sqrtf(0.01f);      // NOISE * sqrt(STEP), f32-exact vs jnp.sqrt(f32(0.01))

  float* xre   = (float*)d_out;
  float* ypred = xre + (size_t)B_*XD_;

  k_prepA  <<<512,  64, 0, stream>>>(saWo, saWqkv, caWo, caWqkv, Sm, Um);
  k_prepB  <<<6,    64, 0, stream>>>(saWo, sabqkv, sabo, caWo, cabqkv, cabo, pxW2, pxb2, vs0, vu0, vcb);
  k_prepM  <<<256,  64, 0, stream>>>(pxW2, Mm);
  k_prepTR <<<2180, 64, 0, stream>>>(Sm, Um, xpW, zpW, xpb, zpb, vs0, vu0, Tm, Rm, vt0, vr0);
  k_prepWX <<<4096, 256, 0, stream>>>(pxW2, Tm, embW, embb, vt0, WX, vq0);
  k_prepW2T<<<2048, 256, 0, stream>>>(pxW2, W2T);
  k_genz0  <<<ZN_/256, 256, 0, stream>>>(z, ks[0][0], ks[0][1]);
  k_xpass  <<<512, 256, 0, stream>>>(x, WX, vcb, vq0, cneg, h1pre);
  for (int s = 0; s < 10; ++s)
    k_step <<<256, 256, 0, stream>>>(z, pxW1, pxb1, Mm, cneg, ks[1+s][0], ks[1+s][1], hstep, nscale);
  k_finalz <<<256, 256, 0, stream>>>(z, pxW1, Rm, pxb1, vr0, hfin, capre);
  k_xrecon <<<256, 256, 0, stream>>>(hfin, W2T, pxb2, xre);
  k_tail   <<<2048, 256, 0, stream>>>(h1pre, capre, ln1g, ln1b, ln2g, ln2b, ln3g, ln3b,
                                      fW1, fb1, fW2, fb2, outW, outb, ypred);
}

// Round 2
// 1369.214 us; speedup vs baseline: 2.0092x; 2.0092x over previous
//
#include <hip/hip_runtime.h>
#include <cstdint>
#include <cstddef>
#include <cmath>

#define B_     8192
#define XD_    4096
#define ZD_    1024
#define XE_    64
#define H_     128
#define ZN_    (B_*ZD_)      /* 8388608 */
#define NHALF_ (ZN_/2)

// JAX threefry mode: 1 = partitionable (modern default) — verified correct in round 1
#define RNG_PARTITIONABLE 1

typedef __attribute__((ext_vector_type(8))) short short8_t;   // 8 x bf16 (4 VGPR)
typedef __attribute__((ext_vector_type(4))) float f32x4_t;    // MFMA accumulator
#define MFMA16(a,b,c) __builtin_amdgcn_mfma_f32_16x16x32_bf16((a),(b),(c),0,0,0)

// ---------------- threefry2x32 (bit-exact vs JAX) ----------------
__host__ __device__ __forceinline__ uint32_t rotl32_(uint32_t x, int r){ return (x<<r)|(x>>(32-r)); }

__host__ __device__ __forceinline__ void tf2x32(uint32_t k0, uint32_t k1,
                                                uint32_t x0, uint32_t x1,
                                                uint32_t* o0, uint32_t* o1){
  uint32_t k2 = k0 ^ k1 ^ 0x1BD11BDAu;
  x0 += k0; x1 += k1;
  x0 += x1; x1 = rotl32_(x1,13); x1 ^= x0;
  x0 += x1; x1 = rotl32_(x1,15); x1 ^= x0;
  x0 += x1; x1 = rotl32_(x1,26); x1 ^= x0;
  x0 += x1; x1 = rotl32_(x1, 6); x1 ^= x0;
  x0 += k1; x1 += k2 + 1u;
  x0 += x1; x1 = rotl32_(x1,17); x1 ^= x0;
  x0 += x1; x1 = rotl32_(x1,29); x1 ^= x0;
  x0 += x1; x1 = rotl32_(x1,16); x1 ^= x0;
  x0 += x1; x1 = rotl32_(x1,24); x1 ^= x0;
  x0 += k2; x1 += k0 + 2u;
  x0 += x1; x1 = rotl32_(x1,13); x1 ^= x0;
  x0 += x1; x1 = rotl32_(x1,15); x1 ^= x0;
  x0 += x1; x1 = rotl32_(x1,26); x1 ^= x0;
  x0 += x1; x1 = rotl32_(x1, 6); x1 ^= x0;
  x0 += k0; x1 += k1 + 3u;
  x0 += x1; x1 = rotl32_(x1,17); x1 ^= x0;
  x0 += x1; x1 = rotl32_(x1,29); x1 ^= x0;
  x0 += x1; x1 = rotl32_(x1,16); x1 ^= x0;
  x0 += x1; x1 = rotl32_(x1,24); x1 ^= x0;
  x0 += k1; x1 += k2 + 4u;
  x0 += x1; x1 = rotl32_(x1,13); x1 ^= x0;
  x0 += x1; x1 = rotl32_(x1,15); x1 ^= x0;
  x0 += x1; x1 = rotl32_(x1,26); x1 ^= x0;
  x0 += x1; x1 = rotl32_(x1, 6); x1 ^= x0;
  x0 += k2; x1 += k0 + 5u;
  *o0 = x0; *o1 = x1;
}

// XLA ErfInv32 (Giles polynomial)
__device__ __forceinline__ float erfinv_(float x){
  float w = -log1pf(-x*x);
  float p;
  if (w < 5.0f){
    w -= 2.5f;
    p = 2.81022636e-08f;
    p = fmaf(p, w, 3.43273939e-07f);
    p = fmaf(p, w, -3.5233877e-06f);
    p = fmaf(p, w, -4.39150654e-06f);
    p = fmaf(p, w, 0.00021858087f);
    p = fmaf(p, w, -0.00125372503f);
    p = fmaf(p, w, -0.00417768164f);
    p = fmaf(p, w, 0.246640727f);
    p = fmaf(p, w, 1.50140941f);
  } else {
    w = sqrtf(w) - 3.0f;
    p = -0.000200214257f;
    p = fmaf(p, w, 0.000100950558f);
    p = fmaf(p, w, 0.00134934322f);
    p = fmaf(p, w, -0.00367342844f);
    p = fmaf(p, w, 0.00573950773f);
    p = fmaf(p, w, -0.0076224613f);
    p = fmaf(p, w, 0.00943887047f);
    p = fmaf(p, w, 1.00167406f);
    p = fmaf(p, w, 2.83297682f);
  }
  return p * x;
}

__device__ __forceinline__ float bits_to_normal(uint32_t bits){
  float f = __uint_as_float((bits >> 9) | 0x3f800000u) - 1.0f;  // [0,1)
  float u = fmaxf(-0.99999994f, fmaf(f, 2.0f, -0.99999994f));
  return 1.41421356f * erfinv_(u);
}

__device__ __forceinline__ float rng_normal(uint32_t k0, uint32_t k1, uint32_t idx){
#if RNG_PARTITIONABLE
  uint32_t o0, o1; tf2x32(k0, k1, 0u, idx, &o0, &o1);
  return bits_to_normal(o0 ^ o1);
#else
  uint32_t i = (idx < NHALF_) ? idx : idx - NHALF_;
  uint32_t o0, o1; tf2x32(k0, k1, i, i + NHALF_, &o0, &o1);
  return bits_to_normal((idx < NHALF_) ? o0 : o1);
#endif
}

// f32 -> bf16 round-to-nearest-even
__device__ __forceinline__ ushort f2bf(float f){
  uint32_t u = __float_as_uint(f);
  return (ushort)((u + 0x7FFFu + ((u >> 16) & 1u)) >> 16);
}

// ---------------- tiny weight-prep kernels (f32) ----------------
__global__ void k_prepA(const float* __restrict__ saWo, const float* __restrict__ saWqkv,
                        const float* __restrict__ caWo, const float* __restrict__ caWqkv,
                        float* __restrict__ S, float* __restrict__ U){
  int blk = blockIdx.x, tid = threadIdx.x;
  int idx = (blk & 255) * 64 + tid;
  int i = idx >> 7, j = idx & 127;
  if (blk < 256){
    float acc = (i == j) ? 1.0f : 0.0f;
    for (int k = 0; k < H_; ++k) acc += saWo[i*H_ + k] * saWqkv[(2*H_ + k)*H_ + j];
    S[idx] = acc;
  } else {
    float acc = 0.0f;
    for (int k = 0; k < H_; ++k) acc += caWo[i*H_ + k] * caWqkv[(2*H_ + k)*H_ + j];
    U[idx] = acc;
  }
}

__global__ void k_prepB(const float* __restrict__ saWo, const float* __restrict__ sabqkv, const float* __restrict__ sabo,
                        const float* __restrict__ caWo, const float* __restrict__ cabqkv, const float* __restrict__ cabo,
                        const float* __restrict__ W2, const float* __restrict__ pb2,
                        float* __restrict__ s0, float* __restrict__ u0, float* __restrict__ cb){
  int blk = blockIdx.x, tid = threadIdx.x;
  if (blk < 2){
    int i = blk*64 + tid;
    float acc = sabo[i];
    for (int k = 0; k < H_; ++k) acc += saWo[i*H_ + k] * sabqkv[2*H_ + k];
    s0[i] = acc;
  } else if (blk < 4){
    int i = (blk-2)*64 + tid;
    float acc = cabo[i];
    for (int k = 0; k < H_; ++k) acc += caWo[i*H_ + k] * cabqkv[2*H_ + k];
    u0[i] = acc;
  } else {
    int j = (blk-4)*64 + tid;
    float acc = 0.0f;
    for (int c = 0; c < XD_; ++c) acc += pb2[c] * W2[(size_t)c*H_ + j];
    cb[j] = acc;
  }
}

__global__ void k_prepM(const float* __restrict__ W2, float* __restrict__ M){
  int idx = blockIdx.x*64 + threadIdx.x;  // 16384
  int j1 = idx >> 7, j2 = idx & 127;
  float acc = 0.0f;
  for (int c = 0; c < XD_; ++c) acc += W2[(size_t)c*H_ + j1] * W2[(size_t)c*H_ + j2];
  M[idx] = acc;
}

__global__ void k_prepTR(const float* __restrict__ S, const float* __restrict__ U,
                         const float* __restrict__ xpW, const float* __restrict__ zpW,
                         const float* __restrict__ xpb, const float* __restrict__ zpb,
                         const float* __restrict__ s0, const float* __restrict__ u0,
                         float* __restrict__ T, float* __restrict__ R,
                         float* __restrict__ t0, float* __restrict__ r0v){
  int blk = blockIdx.x, tid = threadIdx.x;
  if (blk < 128){
    int idx = blk*64 + tid;              // 8192
    int i = idx >> 6, e = idx & 63;
    float acc = 0.0f;
    for (int m = 0; m < H_; ++m) acc += S[i*H_ + m] * xpW[m*XE_ + e];
    T[idx] = acc;
  } else if (blk < 2176){
    int idx = (blk-128)*64 + tid;        // 131072
    int i = idx >> 10, k = idx & 1023;
    float acc = 0.0f;
    for (int m = 0; m < H_; ++m) acc += U[i*H_ + m] * zpW[(size_t)m*ZD_ + k];
    R[idx] = acc;
  } else if (blk < 2178){
    int i = (blk-2176)*64 + tid;
    float acc = s0[i];
    for (int m = 0; m < H_; ++m) acc += S[i*H_ + m] * xpb[m];
    t0[i] = acc;
  } else {
    int i = (blk-2178)*64 + tid;
    float acc = u0[i];
    for (int m = 0; m < H_; ++m) acc += U[i*H_ + m] * zpb[m];
    r0v[i] = acc;
  }
}

// WXT[j][c] (bf16, [256][4096]): j<128 -> W2[c][j] ; j>=128 -> sum_e T[j-128][e]*embW[e][c]
__global__ void k_prepWXT(const float* __restrict__ W2, const float* __restrict__ T,
                          const float* __restrict__ embW, const float* __restrict__ embb,
                          const float* __restrict__ t0,
                          ushort* __restrict__ WXT, float* __restrict__ q0){
  int idx = blockIdx.x*256 + threadIdx.x;   // 1048576
  int j = idx >> 12, c = idx & 4095;
  float v;
  if (j < H_) v = W2[(size_t)c*H_ + j];
  else {
    int i = j - H_;
    float acc = 0.0f;
    for (int e = 0; e < XE_; ++e) acc += T[i*XE_ + e] * embW[(size_t)e*XD_ + c];
    v = acc;
  }
  WXT[idx] = f2bf(v);
  if (idx < H_){
    float acc = t0[idx];
    for (int e = 0; e < XE_; ++e) acc += T[idx*XE_ + e] * embb[e];
    q0[idx] = acc;
  }
}

// bf16 conversions: W2bf[4096*128], W1bf[128*1024], W1Tbf[1024*128], Mbf[128*128], FBT[256*1024]
__global__ void k_conv(const float* __restrict__ W2, const float* __restrict__ W1,
                       const float* __restrict__ Mm, const float* __restrict__ R,
                       ushort* __restrict__ W2bf, ushort* __restrict__ W1bf,
                       ushort* __restrict__ W1Tbf, ushort* __restrict__ Mbf,
                       ushort* __restrict__ FBT){
  int idx = blockIdx.x*256 + threadIdx.x;   // 1064960
  if (idx < 524288) W2bf[idx] = f2bf(W2[idx]);
  else if (idx < 655360){ int i = idx - 524288; W1bf[i] = f2bf(W1[i]); }
  else if (idx < 786432){ int i = idx - 655360; int k = i >> 7, h = i & 127;
    W1Tbf[i] = f2bf(W1[h*ZD_ + k]); }
  else if (idx < 802816){ int i = idx - 786432; Mbf[i] = f2bf(Mm[i]); }
  else { int i = idx - 802816; int j = i >> 10, k = i & 1023;
    FBT[i] = f2bf(j < H_ ? W1[j*ZD_ + k] : R[(size_t)(j-H_)*ZD_ + k]); }
}

// ---------------- z0 generation ----------------
__global__ void k_genz0(float* __restrict__ z, uint32_t k0, uint32_t k1){
  uint32_t i = blockIdx.x*256u + threadIdx.x;
  z[i] = rng_normal(k0, k1, i);
}

// ---------------- x-pass (MFMA): [cneg | h1pre] = x @ WXT^T ----------------
// M=8192 N=256(2 col-tiles of 128) K=4096. BM=64. grid 256.
__global__ __launch_bounds__(256) void k_xpass_mfma(
    const float* __restrict__ x, const ushort* __restrict__ WXT,
    const float* __restrict__ cb, const float* __restrict__ q0,
    float* __restrict__ cneg, float* __restrict__ h1pre){
  __shared__ __align__(16) ushort xt[64*72];
  __shared__ __align__(16) ushort bt[128*72];
  const int tid = threadIdx.x, lane = tid & 63, w = tid >> 6;
  const int bm = blockIdx.x >> 1, bn = blockIdx.x & 1;
  const int row0 = bm*64, ncol0 = bn*128;
  const int l15 = lane & 15, kq8 = (lane >> 4)*8, rq = (lane >> 4)*4;
  f32x4_t acc[8] = {};
  for (int kt = 0; kt < XD_; kt += 64){
    { int r = tid >> 2, kq = (tid & 3)*16;
      const float* src = &x[(size_t)(row0 + r)*XD_ + kt + kq];
      #pragma unroll
      for (int i = 0; i < 4; ++i){
        float4 v = *(const float4*)(src + 4*i);
        union { ushort u[4]; uint2 q; } p;
        p.u[0]=f2bf(v.x); p.u[1]=f2bf(v.y); p.u[2]=f2bf(v.z); p.u[3]=f2bf(v.w);
        *(uint2*)&xt[r*72 + kq + 4*i] = p.q;
      }
    }
    { int n = tid >> 1, kh = (tid & 1)*32;
      const ushort* src = &WXT[(size_t)(ncol0 + n)*XD_ + kt + kh];
      #pragma unroll
      for (int i = 0; i < 4; ++i) *(uint4*)&bt[n*72 + kh + 8*i] = *(const uint4*)(src + 8*i);
    }
    __syncthreads();
    #pragma unroll
    for (int h = 0; h < 2; ++h){
      short8_t a = *(const short8_t*)&xt[(w*16 + l15)*72 + h*32 + kq8];
      #pragma unroll
      for (int nf = 0; nf < 8; ++nf){
        short8_t b = *(const short8_t*)&bt[(nf*16 + l15)*72 + h*32 + kq8];
        acc[nf] = MFMA16(a, b, acc[nf]);
      }
    }
    __syncthreads();
  }
  #pragma unroll
  for (int nf = 0; nf < 8; ++nf){
    int col = nf*16 + l15;
    #pragma unroll
    for (int r = 0; r < 4; ++r){
      int row = row0 + w*16 + rq + r;
      float v = acc[nf][r];
      if (bn == 0) cneg[(size_t)row*H_ + col] = 2.0f*(cb[col] - v);
      else         h1pre[(size_t)row*H_ + col] = v + q0[col];
    }
  }
}

// ---------------- fused Langevin step (MFMA) ----------------
// BM=16 rows/block, grid 512.  P1: h=z@W1^T  P2: g=mask(2*relu(h)@M+cneg)  P3: z -= h*g@W1 (+noise)
__global__ __launch_bounds__(256) void k_step2(
    float* __restrict__ z, const ushort* __restrict__ W1bf,
    const ushort* __restrict__ W1Tbf, const ushort* __restrict__ Mbf,
    const float* __restrict__ b1, const float* __restrict__ cneg,
    uint32_t key0, uint32_t key1){
  __shared__ __align__(16) ushort abuf[16*136];
  __shared__ __align__(16) ushort glbuf[16*136];
  __shared__ __align__(16) ushort big[17408];   // P1/P2: zt[16*72]+bt[128*72] ; P3: bt3[128*136]
  ushort* zt  = big;
  ushort* bt  = big + 16*72;
  ushort* bt3 = big;
  const int tid = threadIdx.x, lane = tid & 63, w = tid >> 6;
  const int b0 = blockIdx.x * 16;
  const int l15 = lane & 15, kq8 = (lane >> 4)*8, rq = (lane >> 4)*4;

  // ---- P1: h[16][128] = z @ W1^T, K=1024 ; wave w -> cols 32w..32w+31
  f32x4_t acc[2] = {};
  for (int kt = 0; kt < ZD_; kt += 64){
    { int r = tid >> 4, k4 = (tid & 15)*4;
      float4 v = *(const float4*)&z[(size_t)(b0 + r)*ZD_ + kt + k4];
      union { ushort u[4]; uint2 q; } p;
      p.u[0]=f2bf(v.x); p.u[1]=f2bf(v.y); p.u[2]=f2bf(v.z); p.u[3]=f2bf(v.w);
      *(uint2*)&zt[r*72 + k4] = p.q;
    }
    { int n = tid >> 1, kh = (tid & 1)*32;
      const ushort* src = &W1bf[(size_t)n*ZD_ + kt + kh];
      #pragma unroll
      for (int i = 0; i < 4; ++i) *(uint4*)&bt[n*72 + kh + 8*i] = *(const uint4*)(src + 8*i);
    }
    __syncthreads();
    #pragma unroll
    for (int h = 0; h < 2; ++h){
      short8_t a = *(const short8_t*)&zt[l15*72 + h*32 + kq8];
      #pragma unroll
      for (int nf = 0; nf < 2; ++nf){
        short8_t b = *(const short8_t*)&bt[(w*32 + nf*16 + l15)*72 + h*32 + kq8];
        acc[nf] = MFMA16(a, b, acc[nf]);
      }
    }
    __syncthreads();
  }
  // a = relu(h + b1) -> abuf (bf16); mask == (abuf != 0)
  #pragma unroll
  for (int nf = 0; nf < 2; ++nf){
    int col = w*32 + nf*16 + l15;
    float bb = b1[col];
    #pragma unroll
    for (int r = 0; r < 4; ++r)
      abuf[(rq + r)*136 + col] = f2bf(fmaxf(acc[nf][r] + bb, 0.0f));
  }
  __syncthreads();

  // ---- P2: g2 = a @ M, K=128 (2 chunks of 64)
  f32x4_t acc2[2] = {};
  for (int c = 0; c < 2; ++c){
    { int n = tid >> 1, kh = (tid & 1)*32;
      const ushort* src = &Mbf[(size_t)n*H_ + c*64 + kh];
      #pragma unroll
      for (int i = 0; i < 4; ++i) *(uint4*)&bt[n*72 + kh + 8*i] = *(const uint4*)(src + 8*i);
    }
    __syncthreads();
    #pragma unroll
    for (int h = 0; h < 2; ++h){
      short8_t a = *(const short8_t*)&abuf[l15*136 + c*64 + h*32 + kq8];
      #pragma unroll
      for (int nf = 0; nf < 2; ++nf){
        short8_t b = *(const short8_t*)&bt[(w*32 + nf*16 + l15)*72 + h*32 + kq8];
        acc2[nf] = MFMA16(a, b, acc2[nf]);
      }
    }
    __syncthreads();
  }
  // g = mask ? 2*g2 + cneg : 0  -> glbuf (bf16)
  #pragma unroll
  for (int nf = 0; nf < 2; ++nf){
    int col = w*32 + nf*16 + l15;
    #pragma unroll
    for (int r = 0; r < 4; ++r){
      int row = rq + r;
      float cn = cneg[(size_t)(b0 + row)*H_ + col];
      float g = (abuf[row*136 + col] != 0) ? fmaf(2.0f, acc2[nf][r], cn) : 0.0f;
      glbuf[row*136 + col] = f2bf(g);
    }
  }
  __syncthreads();

  // ---- P3: z = z - hstep*(g @ W1) + nscale*noise ; 8 col-tiles of 128
  const float hstep = 0.005f, nscale = 0.1f;
  for (int nt = 0; nt < 8; ++nt){
    { int n = tid >> 1, kh = (tid & 1)*64;
      const ushort* src = &W1Tbf[(size_t)(nt*128 + n)*H_ + kh];
      #pragma unroll
      for (int i = 0; i < 8; ++i) *(uint4*)&bt3[n*136 + kh + 8*i] = *(const uint4*)(src + 8*i);
    }
    __syncthreads();
    f32x4_t acc3[2] = {};
    #pragma unroll
    for (int k = 0; k < 4; ++k){
      short8_t a = *(const short8_t*)&glbuf[l15*136 + k*32 + kq8];
      #pragma unroll
      for (int nf = 0; nf < 2; ++nf){
        short8_t b = *(const short8_t*)&bt3[(w*32 + nf*16 + l15)*136 + k*32 + kq8];
        acc3[nf] = MFMA16(a, b, acc3[nf]);
      }
    }
    #pragma unroll
    for (int nf = 0; nf < 2; ++nf){
      int col = nt*128 + w*32 + nf*16 + l15;
      #pragma unroll
      for (int r = 0; r < 4; ++r){
        size_t idx = (size_t)(b0 + rq + r)*ZD_ + col;
        float t = fmaf(-hstep, acc3[nf][r], z[idx]);
        z[idx] = fmaf(nscale, rng_normal(key0, key1, (uint32_t)idx), t);
      }
    }
    __syncthreads();
  }
}

// ---------------- final z pass (MFMA): [hfin_bf | capre] = z @ FBT^T ----------------
// M=8192 N=256 K=1024. BM=32, grid 256. wave: rows (w&1)*16, cols (w>>1)*128.
__global__ __launch_bounds__(256) void k_finalz_mfma(
    const float* __restrict__ z, const ushort* __restrict__ FBT,
    const float* __restrict__ b1, const float* __restrict__ r0v,
    ushort* __restrict__ hfin_bf, float* __restrict__ capre){
  __shared__ __align__(16) ushort zt[32*72];
  __shared__ __align__(16) ushort bt[256*72];
  const int tid = threadIdx.x, lane = tid & 63, w = tid >> 6;
  const int b0 = blockIdx.x * 32;
  const int l15 = lane & 15, kq8 = (lane >> 4)*8, rq = (lane >> 4)*4;
  const int rh = (w & 1)*16, ch = (w >> 1)*128;
  f32x4_t acc[8] = {};
  for (int kt = 0; kt < ZD_; kt += 64){
    { int r = tid >> 3, k8 = (tid & 7)*8;
      const float* src = &z[(size_t)(b0 + r)*ZD_ + kt + k8];
      #pragma unroll
      for (int i = 0; i < 2; ++i){
        float4 v = *(const float4*)(src + 4*i);
        union { ushort u[4]; uint2 q; } p;
        p.u[0]=f2bf(v.x); p.u[1]=f2bf(v.y); p.u[2]=f2bf(v.z); p.u[3]=f2bf(v.w);
        *(uint2*)&zt[r*72 + k8 + 4*i] = p.q;
      }
    }
    { int n = tid;
      const ushort* src = &FBT[(size_t)n*ZD_ + kt];
      #pragma unroll
      for (int i = 0; i < 8; ++i) *(uint4*)&bt[n*72 + 8*i] = *(const uint4*)(src + 8*i);
    }
    __syncthreads();
    #pragma unroll
    for (int h = 0; h < 2; ++h){
      short8_t a = *(const short8_t*)&zt[(rh + l15)*72 + h*32 + kq8];
      #pragma unroll
      for (int nf = 0; nf < 8; ++nf){
        short8_t b = *(const short8_t*)&bt[(ch + nf*16 + l15)*72 + h*32 + kq8];
        acc[nf] = MFMA16(a, b, acc[nf]);
      }
    }
    __syncthreads();
  }
  #pragma unroll
  for (int nf = 0; nf < 8; ++nf){
    int j = ch + nf*16 + l15;
    #pragma unroll
    for (int r = 0; r < 4; ++r){
      int row = b0 + rh + rq + r;
      float v = acc[nf][r];
      if (j < H_) hfin_bf[(size_t)row*H_ + j] = f2bf(fmaxf(v + b1[j], 0.0f));
      else        capre[(size_t)row*H_ + (j - H_)] = v + r0v[j - H_];
    }
  }
}

// ---------------- x_recon (MFMA): out = hfin @ W2^T + b2 ----------------
// M=8192 N=4096 K=128. BM=64 BN=128, grid 4096.
__global__ __launch_bounds__(256) void k_xrecon_mfma(
    const ushort* __restrict__ hfin_bf, const ushort* __restrict__ W2bf,
    const float* __restrict__ b2, float* __restrict__ out){
  __shared__ __align__(16) ushort at[64*136];
  __shared__ __align__(16) ushort bt[128*136];
  const int tid = threadIdx.x, lane = tid & 63, w = tid >> 6;
  const int bm = blockIdx.x >> 5, bn = blockIdx.x & 31;
  const int row0 = bm*64, c0 = bn*128;
  const int l15 = lane & 15, kq8 = (lane >> 4)*8, rq = (lane >> 4)*4;
  { int r = tid >> 2, kq = (tid & 3)*32;
    const ushort* src = &hfin_bf[(size_t)(row0 + r)*H_ + kq];
    #pragma unroll
    for (int i = 0; i < 4; ++i) *(uint4*)&at[r*136 + kq + 8*i] = *(const uint4*)(src + 8*i);
  }
  { int n = tid >> 1, kh = (tid & 1)*64;
    const ushort* src = &W2bf[(size_t)(c0 + n)*H_ + kh];
    #pragma unroll
    for (int i = 0; i < 8; ++i) *(uint4*)&bt[n*136 + kh + 8*i] = *(const uint4*)(src + 8*i);
  }
  __syncthreads();
  f32x4_t acc[8] = {};
  #pragma unroll
  for (int k = 0; k < 4; ++k){
    short8_t a = *(const short8_t*)&at[(w*16 + l15)*136 + k*32 + kq8];
    #pragma unroll
    for (int nf = 0; nf < 8; ++nf){
      short8_t b = *(const short8_t*)&bt[(nf*16 + l15)*136 + k*32 + kq8];
      acc[nf] = MFMA16(a, b, acc[nf]);
    }
  }
  #pragma unroll
  for (int nf = 0; nf < 8; ++nf){
    int c = c0 + nf*16 + l15;
    float bb = b2[c];
    #pragma unroll
    for (int r = 0; r < 4; ++r){
      int row = row0 + w*16 + rq + r;
      out[(size_t)row*XD_ + c] = acc[nf][r] + bb;
    }
  }
}

// ---------------- per-row transformer tail -> y_pred ----------------
__device__ __forceinline__ float wsum64(float v){
  #pragma unroll
  for (int off = 32; off > 0; off >>= 1) v += __shfl_xor(v, off, 64);
  return v;
}

__global__ __launch_bounds__(256) void k_tail(
    const float* __restrict__ h1pre, const float* __restrict__ capre,
    const float* __restrict__ ln1g, const float* __restrict__ ln1b,
    const float* __restrict__ ln2g, const float* __restrict__ ln2b,
    const float* __restrict__ ln3g, const float* __restrict__ ln3b,
    const float* __restrict__ fW1, const float* __restrict__ fb1,
    const float* __restrict__ fW2, const float* __restrict__ fb2,
    const float* __restrict__ outW, const float* __restrict__ outb,
    float* __restrict__ y){
  __shared__ float sh2[4][128];
  __shared__ float st1[4][128];
  const int tid = threadIdx.x;
  const int w = tid >> 6;
  const int l = tid & 63;
  const int b = blockIdx.x * 4 + w;
  const float* hp = h1pre + (size_t)b * H_;
  const float* cp = capre + (size_t)b * H_;
  float x0 = hp[l], x1 = hp[l+64];
  float m = wsum64(x0 + x1) * (1.0f/128.0f);
  float d0 = x0 - m, d1 = x1 - m;
  float v = wsum64(d0*d0 + d1*d1) * (1.0f/128.0f);
  float rs = rsqrtf(v + 1e-5f);
  float h1a = d0 * rs * ln1g[l]    + ln1b[l];
  float h1b = d1 * rs * ln1g[l+64] + ln1b[l+64];
  x0 = h1a + cp[l]; x1 = h1b + cp[l+64];
  m = wsum64(x0 + x1) * (1.0f/128.0f);
  d0 = x0 - m; d1 = x1 - m;
  v = wsum64(d0*d0 + d1*d1) * (1.0f/128.0f);
  rs = rsqrtf(v + 1e-5f);
  float h2a = d0 * rs * ln2g[l]    + ln2b[l];
  float h2b = d1 * rs * ln2g[l+64] + ln2b[l+64];
  sh2[w][l] = h2a; sh2[w][l+64] = h2b;
  __syncthreads();
  float ta = fb1[l], tb = fb1[l+64];
  #pragma unroll 8
  for (int m4 = 0; m4 < H_; m4 += 4){
    float4 hv = *(const float4*)&sh2[w][m4];
    float4 wa = *(const float4*)&fW1[(size_t)l*H_ + m4];
    float4 wb = *(const float4*)&fW1[(size_t)(l+64)*H_ + m4];
    ta = fmaf(wa.x, hv.x, ta); ta = fmaf(wa.y, hv.y, ta); ta = fmaf(wa.z, hv.z, ta); ta = fmaf(wa.w, hv.w, ta);
    tb = fmaf(wb.x, hv.x, tb); tb = fmaf(wb.y, hv.y, tb); tb = fmaf(wb.z, hv.z, tb); tb = fmaf(wb.w, hv.w, tb);
  }
  ta = fmaxf(ta, 0.0f); tb = fmaxf(tb, 0.0f);
  st1[w][l] = ta; st1[w][l+64] = tb;
  __syncthreads();
  float fa = fb2[l], fbv = fb2[l+64];
  #pragma unroll 8
  for (int m4 = 0; m4 < H_; m4 += 4){
    float4 tv = *(const float4*)&st1[w][m4];
    float4 wa = *(const float4*)&fW2[(size_t)l*H_ + m4];
    float4 wb = *(const float4*)&fW2[(size_t)(l+64)*H_ + m4];
    fa  = fmaf(wa.x, tv.x, fa);  fa  = fmaf(wa.y, tv.y, fa);  fa  = fmaf(wa.z, tv.z, fa);  fa  = fmaf(wa.w, tv.w, fa);
    fbv = fmaf(wb.x, tv.x, fbv); fbv = fmaf(wb.y, tv.y, fbv); fbv = fmaf(wb.z, tv.z, fbv); fbv = fmaf(wb.w, tv.w, fbv);
  }
  x0 = h2a + fa; x1 = h2b + fbv;
  m = wsum64(x0 + x1) * (1.0f/128.0f);
  d0 = x0 - m; d1 = x1 - m;
  v = wsum64(d0*d0 + d1*d1) * (1.0f/128.0f);
  rs = rsqrtf(v + 1e-5f);
  float h3a = d0 * rs * ln3g[l]    + ln3b[l];
  float h3b = d1 * rs * ln3g[l+64] + ln3b[l+64];
  float py = wsum64(outW[l]*h3a + outW[l+64]*h3b);
  if (l == 0) y[b] = py + outb[0];
}

// ---------------- host ----------------
static void make_keys(uint32_t ks[11][2]){
#if RNG_PARTITIONABLE
  for (uint32_t i = 0; i < 11; ++i) tf2x32(0u, 42u, 0u, i, &ks[i][0], &ks[i][1]);
#else
  uint32_t out[22];
  for (uint32_t i = 0; i < 11; ++i){
    uint32_t a, b; tf2x32(0u, 42u, i, 11u + i, &a, &b);
    out[i] = a; out[11u + i] = b;
  }
  for (int i = 0; i < 11; ++i){ ks[i][0] = out[2*i]; ks[i][1] = out[2*i+1]; }
#endif
}

extern "C" void kernel_launch(void* const* d_in, const int* in_sizes, int n_in,
                              void* d_out, int out_size, void* d_ws, size_t ws_size,
                              hipStream_t stream){
  const float* x      = (const float*)d_in[0];
  const float* pxW1   = (const float*)d_in[1];
  const float* pxb1   = (const float*)d_in[2];
  const float* pxW2   = (const float*)d_in[3];
  const float* pxb2   = (const float*)d_in[4];
  const float* embW   = (const float*)d_in[5];
  const float* embb   = (const float*)d_in[6];
  const float* xpW    = (const float*)d_in[7];
  const float* xpb    = (const float*)d_in[8];
  const float* zpW    = (const float*)d_in[9];
  const float* zpb    = (const float*)d_in[10];
  const float* saWqkv = (const float*)d_in[11];
  const float* sabqkv = (const float*)d_in[12];
  const float* saWo   = (const float*)d_in[13];
  const float* sabo   = (const float*)d_in[14];
  const float* caWqkv = (const float*)d_in[15];
  const float* cabqkv = (const float*)d_in[16];
  const float* caWo   = (const float*)d_in[17];
  const float* cabo   = (const float*)d_in[18];
  const float* fW1    = (const float*)d_in[19];
  const float* fb1    = (const float*)d_in[20];
  const float* fW2    = (const float*)d_in[21];
  const float* fb2    = (const float*)d_in[22];
  const float* ln1g   = (const float*)d_in[23];
  const float* ln1b   = (const float*)d_in[24];
  const float* ln2g   = (const float*)d_in[25];
  const float* ln2b   = (const float*)d_in[26];
  const float* ln3g   = (const float*)d_in[27];
  const float* ln3b   = (const float*)d_in[28];
  const float* outW   = (const float*)d_in[29];
  const float* outb   = (const float*)d_in[30];
  (void)in_sizes; (void)n_in; (void)out_size; (void)ws_size;

  float* ws    = (float*)d_ws;
  float* z     = ws;                          // 8388608
  float* cneg  = z + (size_t)ZN_;             // 1048576
  float* h1pre = cneg + (size_t)B_*H_;        // 1048576
  float* capre = h1pre + (size_t)B_*H_;       // 1048576
  float* Rm    = capre + (size_t)B_*H_;       // 131072
  float* Mm    = Rm + (size_t)H_*ZD_;         // 16384
  float* Sm    = Mm + H_*H_;                  // 16384
  float* Um    = Sm + H_*H_;                  // 16384
  float* Tm    = Um + H_*H_;                  // 8192
  float* vs0   = Tm + H_*XE_;
  float* vu0   = vs0 + H_;
  float* vt0   = vu0 + H_;
  float* vq0   = vt0 + H_;
  float* vr0   = vq0 + H_;
  float* vcb   = vr0 + H_;
  ushort* us    = (ushort*)(vcb + H_);
  ushort* WXT   = us;                         // 1048576 ushort
  ushort* W2bf  = WXT + (size_t)256*XD_;      // 524288
  ushort* W1bf  = W2bf + (size_t)XD_*H_;      // 131072
  ushort* W1Tbf = W1bf + (size_t)H_*ZD_;      // 131072
  ushort* Mbf   = W1Tbf + (size_t)ZD_*H_;     // 16384
  ushort* FBT   = Mbf + H_*H_;                // 262144
  ushort* hfin  = FBT + (size_t)256*ZD_;      // 1048576

  uint32_t ks[11][2];
  make_keys(ks);

  float* xre   = (float*)d_out;
  float* ypred = xre + (size_t)B_*XD_;

  k_prepA   <<<512,  64, 0, stream>>>(saWo, saWqkv, caWo, caWqkv, Sm, Um);
  k_prepB   <<<6,    64, 0, stream>>>(saWo, sabqkv, sabo, caWo, cabqkv, cabo, pxW2, pxb2, vs0, vu0, vcb);
  k_prepM   <<<256,  64, 0, stream>>>(pxW2, Mm);
  k_prepTR  <<<2180, 64, 0, stream>>>(Sm, Um, xpW, zpW, xpb, zpb, vs0, vu0, Tm, Rm, vt0, vr0);
  k_prepWXT <<<4096, 256, 0, stream>>>(pxW2, Tm, embW, embb, vt0, WXT, vq0);
  k_conv    <<<4160, 256, 0, stream>>>(pxW2, pxW1, Mm, Rm, W2bf, W1bf, W1Tbf, Mbf, FBT);
  k_genz0   <<<ZN_/256, 256, 0, stream>>>(z, ks[0][0], ks[0][1]);
  k_xpass_mfma <<<256, 256, 0, stream>>>(x, WXT, vcb, vq0, cneg, h1pre);
  for (int s = 0; s < 10; ++s)
    k_step2 <<<512, 256, 0, stream>>>(z, W1bf, W1Tbf, Mbf, pxb1, cneg, ks[1+s][0], ks[1+s][1]);
  k_finalz_mfma <<<256, 256, 0, stream>>>(z, FBT, pxb1, vr0, hfin, capre);
  k_xrecon_mfma <<<4096, 256, 0, stream>>>(hfin, W2bf, pxb2, xre);
  k_tail    <<<2048, 256, 0, stream>>>(h1pre, capre, ln1g, ln1b, ln2g, ln2b, ln3g, ln3b,
                                       fW1, fb1, fW2, fb2, outW, outb, ypred);
}